// Round 1
// baseline (271.347 us; speedup 1.0000x reference)
//
#include <hip/hip_runtime.h>

#define SEQ 2048
#define EMB 1024
#define HD 64

typedef short s16x8 __attribute__((ext_vector_type(8)));
typedef float f32x4 __attribute__((ext_vector_type(4)));

__device__ __forceinline__ unsigned short rne_bf16(float f) {
    unsigned int u = __float_as_uint(f);
    u += 0x7FFFu + ((u >> 16) & 1u);
    return (unsigned short)(u >> 16);
}

__device__ __forceinline__ f32x4 mfma_bf16(s16x8 a, s16x8 b, f32x4 c) {
    return __builtin_amdgcn_mfma_f32_16x16x32_bf16(a, b, c, 0, 0, 0);
}

// ---------------------------------------------------------------------------
// Kernel 1: QKV projection.  mode 0: Q = y*Wq+bq ; mode 1: K,V from x.
// Output: Qb,Kb bf16 [B,S,H]; Vt bf16 [B,H,S] (transposed); Vts f32 [B,64,H]
// (per-32-row tile sums of V, used for the masked-ones suffix correction).
// ---------------------------------------------------------------------------
__global__ __launch_bounds__(256) void proj_kernel(
    const float* __restrict__ x, const float* __restrict__ y,
    const float* __restrict__ Wq, const float* __restrict__ bq,
    const float* __restrict__ Wk, const float* __restrict__ bk,
    const float* __restrict__ Wv, const float* __restrict__ bv,
    unsigned short* __restrict__ Qb, unsigned short* __restrict__ Kb,
    unsigned short* __restrict__ Vt, float* __restrict__ Vts)
{
    const int mode = blockIdx.y;
    const int r0 = blockIdx.x * 64;          // flattened row over B*S
    const int tid = threadIdx.x;
    const int wave = tid >> 6, lane = tid & 63;
    const int l15 = lane & 15, quad = lane >> 4;

    __shared__ unsigned short Wt[2][128 * 40]; // [h][e] transposed weights, stride 40 (80B rows, 16B-aligned frags)
    __shared__ float VLDS[64][65];             // V tile bounce for transpose + tile sums

    const float* __restrict__ src = mode ? x : y;
    const float* __restrict__ W0  = mode ? Wk : Wq;

    f32x4 zero = {0.f, 0.f, 0.f, 0.f};
    f32x4 acc0[4], acc1[4];
    #pragma unroll
    for (int i = 0; i < 4; ++i) { acc0[i] = zero; acc1[i] = zero; }

    const int e_l = tid >> 3;          // 0..31  (e within chunk)
    const int hb  = (tid & 7) << 3;    // 0,8,...,56
    const size_t arowoff = (size_t)(r0 + wave * 16 + l15) * EMB;

    int buf = 0;
    for (int c = 0; c < 32; ++c) {
        // ---- stage transposed W chunk into LDS (bf16) ----
        {
            const float* wsrc = W0 + (size_t)(c * 32 + e_l) * HD + hb;
            float4 w0 = *(const float4*)wsrc;
            float4 w1 = *(const float4*)(wsrc + 4);
            unsigned short* d = &Wt[buf][0];
            d[(hb + 0) * 40 + e_l] = rne_bf16(w0.x);
            d[(hb + 1) * 40 + e_l] = rne_bf16(w0.y);
            d[(hb + 2) * 40 + e_l] = rne_bf16(w0.z);
            d[(hb + 3) * 40 + e_l] = rne_bf16(w0.w);
            d[(hb + 4) * 40 + e_l] = rne_bf16(w1.x);
            d[(hb + 5) * 40 + e_l] = rne_bf16(w1.y);
            d[(hb + 6) * 40 + e_l] = rne_bf16(w1.z);
            d[(hb + 7) * 40 + e_l] = rne_bf16(w1.w);
            if (mode) {
                const float* vsrc = Wv + (size_t)(c * 32 + e_l) * HD + hb;
                float4 v0 = *(const float4*)vsrc;
                float4 v1 = *(const float4*)(vsrc + 4);
                d[(64 + hb + 0) * 40 + e_l] = rne_bf16(v0.x);
                d[(64 + hb + 1) * 40 + e_l] = rne_bf16(v0.y);
                d[(64 + hb + 2) * 40 + e_l] = rne_bf16(v0.z);
                d[(64 + hb + 3) * 40 + e_l] = rne_bf16(v0.w);
                d[(64 + hb + 4) * 40 + e_l] = rne_bf16(v1.x);
                d[(64 + hb + 5) * 40 + e_l] = rne_bf16(v1.y);
                d[(64 + hb + 6) * 40 + e_l] = rne_bf16(v1.z);
                d[(64 + hb + 7) * 40 + e_l] = rne_bf16(v1.w);
            }
        }
        __syncthreads();
        // ---- A fragment: 8 contiguous f32 from global, convert to bf16 ----
        const float* asrc = src + arowoff + c * 32 + quad * 8;
        float4 a0 = *(const float4*)asrc;
        float4 a1 = *(const float4*)(asrc + 4);
        s16x8 af;
        af[0] = (short)rne_bf16(a0.x); af[1] = (short)rne_bf16(a0.y);
        af[2] = (short)rne_bf16(a0.z); af[3] = (short)rne_bf16(a0.w);
        af[4] = (short)rne_bf16(a1.x); af[5] = (short)rne_bf16(a1.y);
        af[6] = (short)rne_bf16(a1.z); af[7] = (short)rne_bf16(a1.w);
        #pragma unroll
        for (int nt = 0; nt < 4; ++nt) {
            s16x8 bf0 = *(const s16x8*)&Wt[buf][(nt * 16 + l15) * 40 + quad * 8];
            acc0[nt] = mfma_bf16(af, bf0, acc0[nt]);
            if (mode) {
                s16x8 bf1 = *(const s16x8*)&Wt[buf][(64 + nt * 16 + l15) * 40 + quad * 8];
                acc1[nt] = mfma_bf16(af, bf1, acc1[nt]);
            }
        }
        buf ^= 1;
    }

    // ---- epilogue: Q or K, RNE bf16 stores ----
    {
        const float* __restrict__ bias0 = mode ? bk : bq;
        unsigned short* __restrict__ O0 = mode ? Kb : Qb;
        #pragma unroll
        for (int nt = 0; nt < 4; ++nt) {
            int h = nt * 16 + l15;
            float bs = bias0[h];
            #pragma unroll
            for (int r = 0; r < 4; ++r) {
                int row = r0 + wave * 16 + quad * 4 + r;
                O0[(size_t)row * HD + h] = rne_bf16(acc0[nt][r] + bs);
            }
        }
    }
    if (mode) {
        // V: bounce through LDS for transpose + tile sums
        #pragma unroll
        for (int nt = 0; nt < 4; ++nt) {
            int h = nt * 16 + l15;
            float bs = bv[h];
            #pragma unroll
            for (int r = 0; r < 4; ++r)
                VLDS[wave * 16 + quad * 4 + r][h] = acc1[nt][r] + bs;
        }
        __syncthreads();
        const int bb = r0 >> 11, s0 = r0 & (SEQ - 1);
        {
            int h = tid >> 2, q4 = tid & 3;
            s16x8 o0, o1;
            #pragma unroll
            for (int i = 0; i < 8; ++i) o0[i] = (short)rne_bf16(VLDS[q4 * 16 + i][h]);
            #pragma unroll
            for (int i = 0; i < 8; ++i) o1[i] = (short)rne_bf16(VLDS[q4 * 16 + 8 + i][h]);
            size_t vb = ((size_t)(bb * HD + h) << 11) + s0 + q4 * 16;
            *(s16x8*)&Vt[vb] = o0;
            *(s16x8*)&Vt[vb + 8] = o1;
        }
        if (tid < 128) {
            int h = tid & 63, half = tid >> 6;
            float s = 0.f;
            #pragma unroll
            for (int i = 0; i < 32; ++i) s += VLDS[half * 32 + i][h];
            Vts[(size_t)(bb * 64 + (s0 >> 5) + half) * HD + h] = s;
        }
    }
}

// ---------------------------------------------------------------------------
// Kernel 2: flash-style attention over the lower triangle + analytic
// correction for the "zeroed upper triangle" (weight 1 each).
// Grid (32,8): WG handles q-tiles (p, 63-p) -> uniform 65 k-iterations.
// ---------------------------------------------------------------------------
__global__ __launch_bounds__(256) void attn_kernel(
    const unsigned short* __restrict__ Qb, const unsigned short* __restrict__ Kb,
    const unsigned short* __restrict__ Vt, const float* __restrict__ Vts,
    float* __restrict__ out)
{
    const int b = blockIdx.y;
    const int pair = blockIdx.x;   // 0..31
    const int tid = threadIdx.x;
    const int wave = tid >> 6, lane = tid & 63;
    const int l15 = lane & 15, quad = lane >> 4;
    const int rh = wave >> 1;      // q-row half (0/1)
    const int kh = wave & 1;       // QK col half == PV h half

    __shared__ unsigned short Plds[2][32 * 40];  // P~ bf16, stride 40
    __shared__ float csuf[64];
    __shared__ float lrow[32];

    const s16x8 ONES = {16256, 16256, 16256, 16256, 16256, 16256, 16256, 16256}; // bf16 1.0

    for (int sel = 0; sel < 2; ++sel) {
        const int tq = sel ? (63 - pair) : pair;
        const int qbase = tq * 32;

        __syncthreads();   // protect csuf/lrow reuse across q-tiles
        if (tid < 64) {
            float s = 0.f;
            for (int tt = tq + 1; tt < 64; ++tt)
                s += Vts[(size_t)((b * 64 + tt) << 6) + tid];
            csuf[tid] = s;
        }

        // Q fragments (held across the k loop)
        const int qrow = qbase + rh * 16 + l15;
        const unsigned short* qp = Qb + ((size_t)(b * SEQ + qrow) << 6);
        s16x8 qf0 = *(const s16x8*)(qp + quad * 8);
        s16x8 qf1 = *(const s16x8*)(qp + 32 + quad * 8);

        f32x4 zero = {0.f, 0.f, 0.f, 0.f};
        f32x4 accO0 = zero, accO1 = zero, accL = zero;
        int buf = 0;

        for (int kt = 0; kt <= tq; ++kt) {
            const int kbase = kt * 32;
            const int krow = kbase + kh * 16 + l15;
            const unsigned short* kp = Kb + ((size_t)(b * SEQ + krow) << 6);
            s16x8 kf0 = *(const s16x8*)(kp + quad * 8);
            s16x8 kf1 = *(const s16x8*)(kp + 32 + quad * 8);

            f32x4 p = zero;
            p = mfma_bf16(qf0, kf0, p);
            p = mfma_bf16(qf1, kf1, p);

            const int colg = kbase + kh * 16 + l15;
            #pragma unroll
            for (int r = 0; r < 4; ++r) {
                int rowg = qbase + rh * 16 + quad * 4 + r;
                float sc = p[r] * 0.125f;
                float w_ = (colg <= rowg) ? __expf(sc) : 1.0f; // zeroed-score => weight 1
                Plds[buf][(rh * 16 + quad * 4 + r) * 40 + kh * 16 + l15] = rne_bf16(w_);
            }
            __syncthreads();

            s16x8 pa = *(const s16x8*)&Plds[buf][(rh * 16 + l15) * 40 + quad * 8];
            const unsigned short* vp = Vt + ((size_t)(b * HD + kh * 32 + l15) << 11) + kbase + quad * 8;
            s16x8 vf0 = *(const s16x8*)(vp);
            s16x8 vf1 = *(const s16x8*)(vp + (16 << 11));
            accO0 = mfma_bf16(pa, vf0, accO0);
            accO1 = mfma_bf16(pa, vf1, accO1);
            if (kh == 0) accL = mfma_bf16(pa, ONES, accL); // row sums of P~
            buf ^= 1;
        }

        if (kh == 0 && l15 == 0) {
            #pragma unroll
            for (int r = 0; r < 4; ++r)
                lrow[rh * 16 + quad * 4 + r] = accL[r];
        }
        __syncthreads();

        const float nOnes = (float)(SEQ - qbase - 32); // fully-masked columns beyond the diag tile
        #pragma unroll
        for (int r = 0; r < 4; ++r) {
            int rowl = rh * 16 + quad * 4 + r;
            float denom = lrow[rowl] + nOnes;
            int hg = kh * 32 + l15;
            float o0 = (accO0[r] + csuf[hg]) / denom;
            float o1 = (accO1[r] + csuf[hg + 16]) / denom;
            size_t ob = ((size_t)(b * SEQ + qbase + rowl) << 6);
            out[ob + hg] = o0;
            out[ob + hg + 16] = o1;
        }
    }
}

extern "C" void kernel_launch(void* const* d_in, const int* in_sizes, int n_in,
                              void* d_out, int out_size, void* d_ws, size_t ws_size,
                              hipStream_t stream) {
    const float* x  = (const float*)d_in[0];
    const float* y  = (const float*)d_in[1];
    const float* Wq = (const float*)d_in[2];
    const float* bq = (const float*)d_in[3];
    const float* Wk = (const float*)d_in[4];
    const float* bk = (const float*)d_in[5];
    const float* Wv = (const float*)d_in[6];
    const float* bv = (const float*)d_in[7];
    float* out = (float*)d_out;

    char* ws = (char*)d_ws;
    unsigned short* Qb  = (unsigned short*)(ws);                  // 2 MB
    unsigned short* Kb  = (unsigned short*)(ws + (1u << 21));     // 2 MB
    unsigned short* Vt  = (unsigned short*)(ws + (2u << 21));     // 2 MB
    float*          Vts = (float*)(ws + (3u << 21));              // 128 KB

    proj_kernel<<<dim3(256, 2), 256, 0, stream>>>(x, y, Wq, bq, Wk, bk, Wv, bv, Qb, Kb, Vt, Vts);
    attn_kernel<<<dim3(32, 8), 256, 0, stream>>>(Qb, Kb, Vt, Vts, out);
}

// Round 2
// 265.468 us; speedup vs baseline: 1.0221x; 1.0221x over previous
//
#include <hip/hip_runtime.h>

#define SEQ 2048
#define EMB 1024
#define HD 64

typedef _Float16 f16x8 __attribute__((ext_vector_type(8)));
typedef _Float16 f16x4 __attribute__((ext_vector_type(4)));
typedef float f32x4 __attribute__((ext_vector_type(4)));

__device__ __forceinline__ f32x4 mfma32(f16x8 a, f16x8 b, f32x4 c) {
    return __builtin_amdgcn_mfma_f32_16x16x32_f16(a, b, c, 0, 0, 0);
}
__device__ __forceinline__ f32x4 mfma16(f16x4 a, f16x4 b, f32x4 c) {
    return __builtin_amdgcn_mfma_f32_16x16x16f16(a, b, c, 0, 0, 0);
}

__device__ __forceinline__ void gload_lds16(const void* g, void* l) {
    __builtin_amdgcn_global_load_lds(
        (const __attribute__((address_space(1))) unsigned int*)g,
        (__attribute__((address_space(3))) unsigned int*)l, 16, 0, 0);
}

// ---------------------------------------------------------------------------
// Kernel 0: convert W{q,k,v} f32[1024][64] -> Wt f16[3][64][1024] (transposed)
// ---------------------------------------------------------------------------
__global__ __launch_bounds__(256) void wcvt_kernel(
    const float* __restrict__ Wq, const float* __restrict__ Wk,
    const float* __restrict__ Wv, _Float16* __restrict__ Wt)
{
    const int m = blockIdx.y;
    const float* __restrict__ W = (m == 0) ? Wq : (m == 1) ? Wk : Wv;
    const int e0 = blockIdx.x * 128;
    const int tid = threadIdx.x;
    __shared__ float T[128][65];
    #pragma unroll
    for (int i = 0; i < 32; ++i) {
        int linear = i * 256 + tid;
        int e = linear >> 6, h = linear & 63;
        T[e][h] = W[(size_t)(e0 + e) * 64 + h];
    }
    __syncthreads();
    const int h = tid >> 2, seg = tid & 3;
    _Float16* dst = Wt + ((size_t)m * 64 + h) * 1024 + e0 + seg * 32;
    #pragma unroll
    for (int i = 0; i < 32; i += 8) {
        f16x8 v;
        #pragma unroll
        for (int j = 0; j < 8; ++j) v[j] = (_Float16)T[seg * 32 + i + j][h];
        *(f16x8*)(dst + i) = v;
    }
}

// ---------------------------------------------------------------------------
// Kernel 1: QKV projection. mode 0: Q from y; mode 1: K,V from x.
// global_load_lds staging (wave-private rows, XOR-swizzled cols, no barriers).
// Outputs f16 Qb,Kb [B,S,64]; Vt [B,64,S]; Vts f32 per-16-row V sums [B,128,64].
// ---------------------------------------------------------------------------
__global__ __launch_bounds__(256) void proj_kernel(
    const float* __restrict__ x, const float* __restrict__ y,
    const _Float16* __restrict__ Wt,
    const float* __restrict__ bq, const float* __restrict__ bk,
    const float* __restrict__ bv,
    _Float16* __restrict__ Qb, _Float16* __restrict__ Kb,
    _Float16* __restrict__ Vt, float* __restrict__ Vts)
{
    const int mode = blockIdx.y;
    const int r0 = blockIdx.x * 64;
    const int tid = threadIdx.x;
    const int wave = tid >> 6, lane = tid & 63;
    const int l15 = lane & 15, quad = lane >> 4;

    __shared__ __align__(16) float As[2][8192]; // 2 x (64 rows x 128 cols)

    const float* __restrict__ src = mode ? x : y;
    const _Float16* __restrict__ W0 = Wt + (mode ? 65536 : 0);
    const _Float16* __restrict__ W1 = Wt + 2 * 65536;

    f32x4 zero = {0.f, 0.f, 0.f, 0.f};
    f32x4 acc0[4], acc1[4];
    #pragma unroll
    for (int i = 0; i < 4; ++i) { acc0[i] = zero; acc1[i] = zero; }

    const int rowme = lane >> 5;   // 0/1
    const int cl = lane & 31;

    auto stage = [&](int ch, int buf) {
        #pragma unroll
        for (int j = 0; j < 8; ++j) {
            int row = wave * 16 + j * 2 + rowme;
            int cg = cl ^ (row & 7);
            const float* gp = src + (size_t)(r0 + row) * 1024 + ch * 128 + cg * 4;
            float* lp = &As[buf][wave * 2048 + j * 256];
            gload_lds16(gp, lp);
        }
    };

    stage(0, 0);
    const int rs = l15 & 7;
    const int abase = (wave * 16 + l15) * 128;

    #pragma unroll
    for (int ch = 0; ch < 8; ++ch) {
        const int buf = ch & 1;
        if (ch < 7) {
            stage(ch + 1, buf ^ 1);
            asm volatile("s_waitcnt vmcnt(8)" ::: "memory");
        } else {
            asm volatile("s_waitcnt vmcnt(0)" ::: "memory");
        }
        #pragma unroll
        for (int ks = 0; ks < 4; ++ks) {
            const int u0 = (ks * 8 + quad * 2) ^ rs;
            const int u1 = (ks * 8 + quad * 2 + 1) ^ rs;
            float4 a0 = *(const float4*)&As[buf][abase + u0 * 4];
            float4 a1 = *(const float4*)&As[buf][abase + u1 * 4];
            f16x8 af;
            af[0] = (_Float16)a0.x; af[1] = (_Float16)a0.y;
            af[2] = (_Float16)a0.z; af[3] = (_Float16)a0.w;
            af[4] = (_Float16)a1.x; af[5] = (_Float16)a1.y;
            af[6] = (_Float16)a1.z; af[7] = (_Float16)a1.w;
            const int k0 = ch * 128 + ks * 32;
            #pragma unroll
            for (int nt = 0; nt < 4; ++nt) {
                f16x8 b0 = *(const f16x8*)&W0[(size_t)(nt * 16 + l15) * 1024 + k0 + quad * 8];
                acc0[nt] = mfma32(af, b0, acc0[nt]);
                if (mode) {
                    f16x8 b1 = *(const f16x8*)&W1[(size_t)(nt * 16 + l15) * 1024 + k0 + quad * 8];
                    acc1[nt] = mfma32(af, b1, acc1[nt]);
                }
            }
        }
    }

    // ---- Q/K store ----
    {
        const float* __restrict__ bias0 = mode ? bk : bq;
        _Float16* __restrict__ O0 = mode ? Kb : Qb;
        #pragma unroll
        for (int nt = 0; nt < 4; ++nt) {
            int h = nt * 16 + l15;
            float bs = bias0[h];
            #pragma unroll
            for (int r = 0; r < 4; ++r) {
                int row = r0 + wave * 16 + quad * 4 + r;
                O0[(size_t)row * 64 + h] = (_Float16)(acc0[nt][r] + bs);
            }
        }
    }
    if (mode) {
        __syncthreads(); // all waves done reading As before aliasing it
        float (*VLDS)[65] = (float(*)[65])&As[0][0];
        #pragma unroll
        for (int nt = 0; nt < 4; ++nt) {
            int h = nt * 16 + l15;
            float bs = bv[h];
            #pragma unroll
            for (int r = 0; r < 4; ++r)
                VLDS[wave * 16 + quad * 4 + r][h] = acc1[nt][r] + bs;
        }
        __syncthreads();
        const int bb = r0 >> 11, s0 = r0 & (SEQ - 1);
        {
            int h = tid >> 2, q4 = tid & 3;
            f16x8 o0, o1;
            #pragma unroll
            for (int i = 0; i < 8; ++i) o0[i] = (_Float16)VLDS[q4 * 16 + i][h];
            #pragma unroll
            for (int i = 0; i < 8; ++i) o1[i] = (_Float16)VLDS[q4 * 16 + 8 + i][h];
            size_t vb = ((size_t)(bb * 64 + h) << 11) + s0 + q4 * 16;
            *(f16x8*)&Vt[vb] = o0;
            *(f16x8*)&Vt[vb + 8] = o1;
        }
        {
            int h = tid & 63;
            float s = 0.f;
            #pragma unroll
            for (int i = 0; i < 16; ++i) s += VLDS[wave * 16 + i][h];
            Vts[((size_t)bb * 128 + (s0 >> 4) + wave) * 64 + h] = s;
        }
    }
}

// ---------------------------------------------------------------------------
// Kernel 2: suffix sums of 16-row V tile sums: Vsuf[b][t][h] = sum_{tt>=t} Vts
// ---------------------------------------------------------------------------
__global__ __launch_bounds__(512) void vsuf_kernel(
    const float* __restrict__ Vts, float* __restrict__ Vsuf)
{
    const int b = blockIdx.x;
    const int tid = threadIdx.x;
    const int seg = tid >> 6, h = tid & 63;
    __shared__ float segsum[8][64];
    float vals[16];
    const float* src = Vts + ((size_t)b * 128 + seg * 16) * 64 + h;
    float s = 0.f;
    #pragma unroll
    for (int i = 0; i < 16; ++i) { vals[i] = src[i * 64]; }
    #pragma unroll
    for (int i = 0; i < 16; ++i) s += vals[i];
    segsum[seg][h] = s;
    __syncthreads();
    float run = 0.f;
    #pragma unroll
    for (int ss = 7; ss >= 0; --ss) if (ss > seg) run += segsum[ss][h];
    float* dst = Vsuf + ((size_t)b * 128 + seg * 16) * 64 + h;
    #pragma unroll
    for (int i = 15; i >= 0; --i) { run += vals[i]; dst[i * 64] = run; }
}

// ---------------------------------------------------------------------------
// Kernel 3: attention. S^T = K·Q^T so P (C-layout) feeds PV 16x16x16 MFMA as
// the B operand directly from registers. No barriers in the k-loop; 4 waves
// split the k-range of q-tiles (t, 127-t); LDS reduction at the end.
// ---------------------------------------------------------------------------
__global__ __launch_bounds__(256) void attn_kernel(
    const _Float16* __restrict__ Qb, const _Float16* __restrict__ Kb,
    const _Float16* __restrict__ Vt, const float* __restrict__ Vsuf,
    float* __restrict__ out)
{
    const int b = blockIdx.y;
    const int tpair = blockIdx.x;  // 0..63
    const int tid = threadIdx.x;
    const int wave = tid >> 6, lane = tid & 63;
    const int l15 = lane & 15, quad = lane >> 4;

    __shared__ float part[4][16][68];
    __shared__ float lpart[4][16];

    const f16x4 ONES4 = {(_Float16)1.f, (_Float16)1.f, (_Float16)1.f, (_Float16)1.f};
    f32x4 zero = {0.f, 0.f, 0.f, 0.f};

    #pragma unroll 1
    for (int sel = 0; sel < 2; ++sel) {
        const int tq = sel ? (127 - tpair) : tpair;
        const int qbase = tq * 16;
        const int nchunks = tq + 1;

        const _Float16* qp = Qb + ((size_t)(b * SEQ + qbase + l15) << 6);
        f16x8 qf0 = *(const f16x8*)(qp + quad * 8);
        f16x8 qf1 = *(const f16x8*)(qp + 32 + quad * 8);

        f32x4 accO[4];
        #pragma unroll
        for (int i = 0; i < 4; ++i) accO[i] = zero;
        f32x4 accL = zero;

        const _Float16* vp0 = Vt + ((size_t)(b * 64 + l15) << 11) + quad * 4;
        const int qg = qbase + l15;

        for (int kc = wave; kc < nchunks; kc += 4) {
            const int kbase = kc << 4;
            const _Float16* kp = Kb + ((size_t)(b * SEQ + kbase + l15) << 6);
            f16x8 kf0 = *(const f16x8*)(kp + quad * 8);
            f16x8 kf1 = *(const f16x8*)(kp + 32 + quad * 8);
            f32x4 s = zero;
            s = mfma32(kf0, qf0, s);   // S^T tile: rows=k, cols=q
            s = mfma32(kf1, qf1, s);
            f16x4 pf;
            const int kq = kbase + quad * 4;
            #pragma unroll
            for (int r = 0; r < 4; ++r) {
                float w = (kq + r <= qg) ? __expf(s[r] * 0.125f) : 1.0f;
                pf[r] = (_Float16)w;
            }
            const _Float16* vp = vp0 + kbase;
            #pragma unroll
            for (int ht = 0; ht < 4; ++ht) {
                f16x4 vf = *(const f16x4*)(vp + ((size_t)ht << 15));
                accO[ht] = mfma16(vf, pf, accO[ht]);  // O^T += V^T · P^T
            }
            accL = mfma16(ONES4, pf, accL);           // row sums of P
        }

        #pragma unroll
        for (int ht = 0; ht < 4; ++ht)
            #pragma unroll
            for (int r = 0; r < 4; ++r)
                part[wave][l15][ht * 16 + quad * 4 + r] = accO[ht][r];
        if (quad == 0) lpart[wave][l15] = accL[0];
        __syncthreads();

        {
            const int q = tid >> 4, hb = (tid & 15) << 2;
            f32x4 o = zero;
            float l = 0.f;
            #pragma unroll
            for (int w = 0; w < 4; ++w) {
                f32x4 pw = *(const f32x4*)&part[w][q][hb];
                o = o + pw;
                l += lpart[w][q];
            }
            const int tend = tq + 1;
            const float nOnes = (float)(SEQ - (tend << 4));
            f32x4 cs = zero;
            if (tend < 128)
                cs = *(const f32x4*)&Vsuf[((size_t)(b * 128 + tend) << 6) + hb];
            const float inv = 1.0f / (l + nOnes);
            f32x4 res = (o + cs) * inv;
            *(f32x4*)&out[((size_t)(b * SEQ + qbase + q) << 6) + hb] = res;
        }
        __syncthreads();
    }
}

extern "C" void kernel_launch(void* const* d_in, const int* in_sizes, int n_in,
                              void* d_out, int out_size, void* d_ws, size_t ws_size,
                              hipStream_t stream) {
    const float* x  = (const float*)d_in[0];
    const float* y  = (const float*)d_in[1];
    const float* Wq = (const float*)d_in[2];
    const float* bq = (const float*)d_in[3];
    const float* Wk = (const float*)d_in[4];
    const float* bk = (const float*)d_in[5];
    const float* Wv = (const float*)d_in[6];
    const float* bv = (const float*)d_in[7];
    float* out = (float*)d_out;

    char* ws = (char*)d_ws;
    _Float16* Qb  = (_Float16*)(ws);                         // 2 MB
    _Float16* Kb  = (_Float16*)(ws + (1u << 21));            // 2 MB
    _Float16* Vt  = (_Float16*)(ws + (2u << 21));            // 2 MB
    _Float16* Wt  = (_Float16*)(ws + (3u << 21));            // 384 KB
    float*    Vts = (float*)(ws + (3u << 21) + (512u << 10));// 256 KB
    float*    Vsf = (float*)(ws + (3u << 21) + (768u << 10));// 256 KB

    wcvt_kernel<<<dim3(8, 3), 256, 0, stream>>>(Wq, Wk, Wv, Wt);
    proj_kernel<<<dim3(256, 2), 256, 0, stream>>>(x, y, Wt, bq, bk, bv, Qb, Kb, Vt, Vts);
    vsuf_kernel<<<dim3(8), 512, 0, stream>>>(Vts, Vsf);
    attn_kernel<<<dim3(64, 8), 256, 0, stream>>>(Qb, Kb, Vt, Vsf, out);
}

// Round 3
// 210.048 us; speedup vs baseline: 1.2918x; 1.2638x over previous
//
#include <hip/hip_runtime.h>

#define SEQ 2048
#define EMB 1024
#define HD 64

typedef _Float16 f16x8 __attribute__((ext_vector_type(8)));
typedef _Float16 f16x4 __attribute__((ext_vector_type(4)));
typedef float f32x4 __attribute__((ext_vector_type(4)));

__device__ __forceinline__ f32x4 mfma32(f16x8 a, f16x8 b, f32x4 c) {
    return __builtin_amdgcn_mfma_f32_16x16x32_f16(a, b, c, 0, 0, 0);
}
__device__ __forceinline__ f32x4 mfma16(f16x4 a, f16x4 b, f32x4 c) {
    return __builtin_amdgcn_mfma_f32_16x16x16f16(a, b, c, 0, 0, 0);
}

// ---------------------------------------------------------------------------
// Kernel 0: pack W{q,k,v} f32[1024][64] into MFMA B-fragment order:
// Wf[(m*4+nt)*32 + kc][lane][8] : element j = W[kc*32 + (lane>>4)*8 + j][nt*16 + (lane&15)]
// ---------------------------------------------------------------------------
__global__ __launch_bounds__(256) void wcvt_kernel(
    const float* __restrict__ Wq, const float* __restrict__ Wk,
    const float* __restrict__ Wv, _Float16* __restrict__ Wf)
{
    const int m = blockIdx.x >> 2, nt = blockIdx.x & 3;
    const float* __restrict__ W = (m == 0) ? Wq : (m == 1) ? Wk : Wv;
    const int tid = threadIdx.x;
    #pragma unroll
    for (int i = 0; i < 8; ++i) {
        int linear = i * 256 + tid;
        int kc = linear >> 6, ln = linear & 63;
        int q8 = (ln >> 4) * 8, l = ln & 15;
        f16x8 w;
        #pragma unroll
        for (int j = 0; j < 8; ++j)
            w[j] = (_Float16)W[(size_t)(kc * 32 + q8 + j) * 64 + nt * 16 + l];
        *(f16x8*)&Wf[((size_t)((m * 4 + nt) * 32 + kc)) * 512 + (size_t)ln * 8] = w;
    }
}

// ---------------------------------------------------------------------------
// Kernel 1: QKV projection. mode 0: Q from y -> Qb [B,S,64].
// mode 1: K,V from x -> Kf (QK A-fragment order), Vf (PV A-fragment order),
// Vts (per-16-row V sums). No LDS / no barriers in the K-loop.
// ---------------------------------------------------------------------------
__global__ __launch_bounds__(256) void proj_kernel(
    const float* __restrict__ x, const float* __restrict__ y,
    const _Float16* __restrict__ Wf,
    const float* __restrict__ bq, const float* __restrict__ bk,
    const float* __restrict__ bv,
    _Float16* __restrict__ Qb, _Float16* __restrict__ Kf,
    _Float16* __restrict__ Vf, float* __restrict__ Vts)
{
    const int mode = blockIdx.y;
    const int r0 = blockIdx.x * 64;
    const int tid = threadIdx.x;
    const int wave = tid >> 6, lane = tid & 63;
    const int l15 = lane & 15, quad = lane >> 4;

    __shared__ float TL[64][65];   // epilogue transpose bounce only (16.6 KB)

    const float* __restrict__ src = mode ? x : y;
    const _Float16* __restrict__ WA = Wf + (mode ? 65536 : 0);
    const _Float16* __restrict__ WB = Wf + 131072;

    f32x4 zero = {0.f, 0.f, 0.f, 0.f};
    f32x4 acc0[4], acc1[4];
    #pragma unroll
    for (int i = 0; i < 4; ++i) { acc0[i] = zero; acc1[i] = zero; }

    const float* arow = src + (size_t)(r0 + wave * 16 + l15) * 1024 + quad * 8;
    const int lo8 = lane * 8;

    #pragma unroll 4
    for (int kc = 0; kc < 32; ++kc) {
        float4 a0 = *(const float4*)(arow + kc * 32);
        float4 a1 = *(const float4*)(arow + kc * 32 + 4);
        f16x8 af;
        af[0] = (_Float16)a0.x; af[1] = (_Float16)a0.y;
        af[2] = (_Float16)a0.z; af[3] = (_Float16)a0.w;
        af[4] = (_Float16)a1.x; af[5] = (_Float16)a1.y;
        af[6] = (_Float16)a1.z; af[7] = (_Float16)a1.w;
        #pragma unroll
        for (int nt = 0; nt < 4; ++nt) {
            f16x8 b0 = *(const f16x8*)&WA[((size_t)(nt * 32 + kc)) * 512 + lo8];
            acc0[nt] = mfma32(af, b0, acc0[nt]);
        }
        if (mode) {
            #pragma unroll
            for (int nt = 0; nt < 4; ++nt) {
                f16x8 b1 = *(const f16x8*)&WB[((size_t)(nt * 32 + kc)) * 512 + lo8];
                acc1[nt] = mfma32(af, b1, acc1[nt]);
            }
        }
    }

    if (mode == 0) {
        #pragma unroll
        for (int nt = 0; nt < 4; ++nt) {
            int h = nt * 16 + l15;
            float bs = bq[h];
            #pragma unroll
            for (int r = 0; r < 4; ++r) {
                int row = r0 + wave * 16 + quad * 4 + r;
                Qb[(size_t)row * 64 + h] = (_Float16)(acc0[nt][r] + bs);
            }
        }
    } else {
        const int bb = r0 >> 11, s0 = r0 & (SEQ - 1);
        // ---- K -> TL -> Kf (fragment order: [kc][half][lane][8]) ----
        #pragma unroll
        for (int nt = 0; nt < 4; ++nt) {
            int h = nt * 16 + l15;
            float bs = bk[h];
            #pragma unroll
            for (int r = 0; r < 4; ++r)
                TL[wave * 16 + quad * 4 + r][h] = acc0[nt][r] + bs;
        }
        __syncthreads();
        {
            int c = tid >> 6, ln = tid & 63, q8 = (ln >> 4) * 8, l = ln & 15;
            #pragma unroll
            for (int half = 0; half < 2; ++half) {
                f16x8 w;
                #pragma unroll
                for (int j = 0; j < 8; ++j)
                    w[j] = (_Float16)TL[c * 16 + l][half * 32 + q8 + j];
                *(f16x8*)&Kf[(((size_t)(bb * 128 + (s0 >> 4) + c)) * 2 + half) * 512 + ln * 8] = w;
            }
        }
        __syncthreads();
        // ---- V -> TL -> Vf (fragment order: [kc2][ht][lane][8], j<4 even chunk) ----
        #pragma unroll
        for (int nt = 0; nt < 4; ++nt) {
            int h = nt * 16 + l15;
            float bs = bv[h];
            #pragma unroll
            for (int r = 0; r < 4; ++r)
                TL[wave * 16 + quad * 4 + r][h] = acc1[nt][r] + bs;
        }
        __syncthreads();
        {
            int ht = tid >> 6, ln = tid & 63, q4 = (ln >> 4) * 4, l = ln & 15;
            #pragma unroll
            for (int c2 = 0; c2 < 2; ++c2) {
                f16x8 w;
                #pragma unroll
                for (int j = 0; j < 8; ++j)
                    w[j] = (_Float16)TL[c2 * 32 + ((j >> 2) << 4) + q4 + (j & 3)][ht * 16 + l];
                *(f16x8*)&Vf[(((size_t)(bb * 64 + (s0 >> 5) + c2)) * 4 + ht) * 512 + ln * 8] = w;
            }
            int h = tid & 63, wv = tid >> 6;
            float s = 0.f;
            #pragma unroll
            for (int i = 0; i < 16; ++i) s += TL[wv * 16 + i][h];
            Vts[((size_t)bb * 128 + (s0 >> 4) + wv) * 64 + h] = s;
        }
    }
}

// ---------------------------------------------------------------------------
// Kernel 2: suffix sums of 16-row V tile sums.
// ---------------------------------------------------------------------------
__global__ __launch_bounds__(256) void vsuf_kernel(
    const float* __restrict__ Vts, float* __restrict__ Vsuf)
{
    const int b = blockIdx.x, hh = blockIdx.y;
    const int tid = threadIdx.x;
    const int seg = tid >> 5, hl = tid & 31, h = (hh << 5) + hl;
    __shared__ float segsum[8][33];
    float vals[16];
    const float* src = Vts + ((size_t)b * 128 + seg * 16) * 64 + h;
    float s = 0.f;
    #pragma unroll
    for (int i = 0; i < 16; ++i) { vals[i] = src[i * 64]; s += vals[i]; }
    segsum[seg][hl] = s;
    __syncthreads();
    float run = 0.f;
    #pragma unroll
    for (int ss = 7; ss >= 0; --ss) if (ss > seg) run += segsum[ss][hl];
    float* dst = Vsuf + ((size_t)b * 128 + seg * 16) * 64 + h;
    #pragma unroll
    for (int i = 15; i >= 0; --i) { run += vals[i]; dst[i * 64] = run; }
}

// ---------------------------------------------------------------------------
// Kernel 3: attention. S^T = K·Q^T (C-layout == PV B-operand layout, P stays
// in registers). All K/V loads are contiguous fragment loads; manual
// double-buffer prefetch; 2 k-chunks per iteration; zero barriers in k-loop.
// ---------------------------------------------------------------------------
__global__ __launch_bounds__(256) void attn_kernel(
    const _Float16* __restrict__ Qb, const _Float16* __restrict__ Kf,
    const _Float16* __restrict__ Vf, const float* __restrict__ Vsuf,
    float* __restrict__ out)
{
    const int b = blockIdx.y;
    const int tpair = blockIdx.x;  // 0..63
    const int tid = threadIdx.x;
    const int wave = tid >> 6, lane = tid & 63;
    const int l15 = lane & 15, quad = lane >> 4;

    __shared__ float part[4][16][68];
    __shared__ float lpart[4][16];

    const f16x4 ONES4 = {(_Float16)1.f, (_Float16)1.f, (_Float16)1.f, (_Float16)1.f};
    f32x4 zero = {0.f, 0.f, 0.f, 0.f};

    const _Float16* __restrict__ kfb = Kf + (size_t)b * 131072 + lane * 8;
    const _Float16* __restrict__ vfb = Vf + (size_t)b * 131072 + lane * 8;

    #pragma unroll 1
    for (int sel = 0; sel < 2; ++sel) {
        const int tq = sel ? (127 - tpair) : tpair;
        const int qbase = tq << 4;
        const int nk2 = (tq >> 1) + 1;   // ceil((tq+1)/2) 2-chunk iterations

        const _Float16* qp = Qb + ((size_t)(b * SEQ + qbase + l15) << 6);
        f16x8 qf0 = *(const f16x8*)(qp + quad * 8);
        f16x8 qf1 = *(const f16x8*)(qp + 32 + quad * 8);

        f32x4 accO[4];
        #pragma unroll
        for (int i = 0; i < 4; ++i) accO[i] = zero;
        f32x4 accL = zero;
        const int qg = qbase + l15;

        f16x8 R0[8], R1[8];
        int kc2 = wave;
        {
            int i0 = (kc2 < nk2) ? kc2 : 0;
            const _Float16* kp = kfb + (size_t)i0 * 2048;
            const _Float16* vp = vfb + (size_t)i0 * 2048;
            R0[0] = *(const f16x8*)(kp);        R0[1] = *(const f16x8*)(kp + 512);
            R0[2] = *(const f16x8*)(kp + 1024); R0[3] = *(const f16x8*)(kp + 1536);
            R0[4] = *(const f16x8*)(vp);        R0[5] = *(const f16x8*)(vp + 512);
            R0[6] = *(const f16x8*)(vp + 1024); R0[7] = *(const f16x8*)(vp + 1536);
        }

        for (; kc2 < nk2; kc2 += 4) {
            int nx = kc2 + 4;
            int nxi = (nx < nk2) ? nx : kc2;
            {
                const _Float16* kp = kfb + (size_t)nxi * 2048;
                const _Float16* vp = vfb + (size_t)nxi * 2048;
                R1[0] = *(const f16x8*)(kp);        R1[1] = *(const f16x8*)(kp + 512);
                R1[2] = *(const f16x8*)(kp + 1024); R1[3] = *(const f16x8*)(kp + 1536);
                R1[4] = *(const f16x8*)(vp);        R1[5] = *(const f16x8*)(vp + 512);
                R1[6] = *(const f16x8*)(vp + 1024); R1[7] = *(const f16x8*)(vp + 1536);
            }
            #pragma unroll
            for (int c = 0; c < 2; ++c) {
                const int kc = 2 * kc2 + c;
                f32x4 s = zero;
                s = mfma32(R0[2 * c], qf0, s);
                s = mfma32(R0[2 * c + 1], qf1, s);
                const float oneval = (kc <= tq) ? 1.0f : 0.0f;
                const int kqb = (kc << 4) + (quad << 2);
                f16x4 pf;
                #pragma unroll
                for (int r = 0; r < 4; ++r) {
                    float w = (kqb + r <= qg) ? __expf(s[r] * 0.125f) : oneval;
                    pf[r] = (_Float16)w;
                }
                #pragma unroll
                for (int ht = 0; ht < 4; ++ht) {
                    f16x8 vv = R0[4 + ht];
                    f16x4 vh;
                    if (c == 0) { vh[0] = vv[0]; vh[1] = vv[1]; vh[2] = vv[2]; vh[3] = vv[3]; }
                    else        { vh[0] = vv[4]; vh[1] = vv[5]; vh[2] = vv[6]; vh[3] = vv[7]; }
                    accO[ht] = mfma16(vh, pf, accO[ht]);
                }
                accL = mfma16(ONES4, pf, accL);
            }
            #pragma unroll
            for (int i = 0; i < 8; ++i) R0[i] = R1[i];
        }

        #pragma unroll
        for (int ht = 0; ht < 4; ++ht)
            #pragma unroll
            for (int r = 0; r < 4; ++r)
                part[wave][l15][ht * 16 + quad * 4 + r] = accO[ht][r];
        if (quad == 0) lpart[wave][l15] = accL[0];
        __syncthreads();

        {
            const int q = tid >> 4, hb = (tid & 15) << 2;
            f32x4 o = zero;
            float l = 0.f;
            #pragma unroll
            for (int w = 0; w < 4; ++w) {
                f32x4 pw = *(const f32x4*)&part[w][q][hb];
                o = o + pw;
                l += lpart[w][q];
            }
            const int tend = tq + 1;
            const float nOnes = (float)(SEQ - (tend << 4));
            f32x4 cs = zero;
            if (tend < 128)
                cs = *(const f32x4*)&Vsuf[((size_t)(b * 128 + tend) << 6) + hb];
            const float inv = 1.0f / (l + nOnes);
            f32x4 res = (o + cs) * inv;
            *(f32x4*)&out[((size_t)(b * SEQ + qbase + q) << 6) + hb] = res;
        }
        __syncthreads();
    }
}

extern "C" void kernel_launch(void* const* d_in, const int* in_sizes, int n_in,
                              void* d_out, int out_size, void* d_ws, size_t ws_size,
                              hipStream_t stream) {
    const float* x  = (const float*)d_in[0];
    const float* y  = (const float*)d_in[1];
    const float* Wq = (const float*)d_in[2];
    const float* bq = (const float*)d_in[3];
    const float* Wk = (const float*)d_in[4];
    const float* bk = (const float*)d_in[5];
    const float* Wv = (const float*)d_in[6];
    const float* bv = (const float*)d_in[7];
    float* out = (float*)d_out;

    char* ws = (char*)d_ws;
    _Float16* Qb  = (_Float16*)(ws);                           // 2 MB
    _Float16* Kf  = (_Float16*)(ws + (1u << 21));              // 2 MB
    _Float16* Vf  = (_Float16*)(ws + (2u << 21));              // 2 MB
    _Float16* Wf  = (_Float16*)(ws + (3u << 21));              // 384 KB
    float*    Vts = (float*)(ws + (3u << 21) + (512u << 10));  // 256 KB
    float*    Vsf = (float*)(ws + (3u << 21) + (768u << 10));  // 256 KB

    wcvt_kernel<<<dim3(12), 256, 0, stream>>>(Wq, Wk, Wv, Wf);
    proj_kernel<<<dim3(256, 2), 256, 0, stream>>>(x, y, Wf, bq, bk, bv, Qb, Kf, Vf, Vts);
    vsuf_kernel<<<dim3(8, 2), 256, 0, stream>>>(Vts, Vsf);
    attn_kernel<<<dim3(64, 8), 256, 0, stream>>>(Qb, Kf, Vf, Vsf, out);
}

// Round 4
// 197.220 us; speedup vs baseline: 1.3759x; 1.0650x over previous
//
#include <hip/hip_runtime.h>

#define SEQ 2048
#define EMB 1024
#define HD 64

typedef _Float16 f16x8 __attribute__((ext_vector_type(8)));
typedef _Float16 f16x4 __attribute__((ext_vector_type(4)));
typedef float f32x4 __attribute__((ext_vector_type(4)));

__device__ __forceinline__ f32x4 mfma32(f16x8 a, f16x8 b, f32x4 c) {
    return __builtin_amdgcn_mfma_f32_16x16x32_f16(a, b, c, 0, 0, 0);
}
__device__ __forceinline__ f32x4 mfma16(f16x4 a, f16x4 b, f32x4 c) {
    return __builtin_amdgcn_mfma_f32_16x16x16f16(a, b, c, 0, 0, 0);
}

// ---------------------------------------------------------------------------
// Kernel 0: pack W{q,k,v} f32[1024][64] into MFMA B-fragment order:
// Wf[(m*4+nt)*32 + kc][lane][8] : elem j = W[kc*32 + (lane>>4)*8 + j][nt*16 + (lane&15)]
// ---------------------------------------------------------------------------
__global__ __launch_bounds__(256) void wcvt_kernel(
    const float* __restrict__ Wq, const float* __restrict__ Wk,
    const float* __restrict__ Wv, _Float16* __restrict__ Wf)
{
    const int m = blockIdx.x >> 2, nt = blockIdx.x & 3;
    const float* __restrict__ W = (m == 0) ? Wq : (m == 1) ? Wk : Wv;
    const int tid = threadIdx.x;
    #pragma unroll
    for (int i = 0; i < 8; ++i) {
        int linear = i * 256 + tid;
        int kc = linear >> 6, ln = linear & 63;
        int q8 = (ln >> 4) * 8, l = ln & 15;
        f16x8 w;
        #pragma unroll
        for (int j = 0; j < 8; ++j)
            w[j] = (_Float16)W[(size_t)(kc * 32 + q8 + j) * 64 + nt * 16 + l];
        *(f16x8*)&Wf[((size_t)((m * 4 + nt) * 32 + kc)) * 512 + (size_t)ln * 8] = w;
    }
}

// ---------------------------------------------------------------------------
// Kernel 1: QKV projection, 512 threads = 8 waves: 4 row-groups x 2 K-halves.
// Explicit register pipeline: A depth-4, B depth-2 ping-pong. Partial-K sums
// combined through LDS in the epilogue.
// ---------------------------------------------------------------------------
__global__ __launch_bounds__(512) void proj_kernel(
    const float* __restrict__ x, const float* __restrict__ y,
    const _Float16* __restrict__ Wf,
    const float* __restrict__ bq, const float* __restrict__ bk,
    const float* __restrict__ bv,
    _Float16* __restrict__ Qb, _Float16* __restrict__ Kf,
    _Float16* __restrict__ Vf, float* __restrict__ Vts)
{
    const int mode = blockIdx.y;
    const int r0 = blockIdx.x * 64;
    const int tid = threadIdx.x;
    const int wave = tid >> 6, lane = tid & 63;
    const int l15 = lane & 15, quad = lane >> 4;
    const int rowgrp = wave >> 1, khalf = wave & 1;

    __shared__ float TL[64][65];

    const float* __restrict__ src = mode ? x : y;
    const _Float16* __restrict__ WA = Wf + (mode ? 65536 : 0);
    const _Float16* __restrict__ WB = Wf + 131072;

    f32x4 zero = {0.f, 0.f, 0.f, 0.f};
    f32x4 acc0[4], acc1[4];
    #pragma unroll
    for (int i = 0; i < 4; ++i) { acc0[i] = zero; acc1[i] = zero; }

    const float* arow = src + (size_t)(r0 + rowgrp * 16 + l15) * 1024 + khalf * 512 + quad * 8;
    const int lo8 = lane * 8;
    const int kb = khalf * 16;

    float4 A0[4], A1[4];
    f16x8 Bq[2][4], Bv[2][4];

    auto LDA = [&](int d, int kc) {
        const float4* p = (const float4*)(arow + kc * 32);
        A0[d] = p[0]; A1[d] = p[1];
    };
    auto LDB = [&](int d, int kc) {
        #pragma unroll
        for (int nt = 0; nt < 4; ++nt)
            Bq[d][nt] = *(const f16x8*)&WA[((size_t)(nt * 32 + kb + kc)) * 512 + lo8];
        if (mode) {
            #pragma unroll
            for (int nt = 0; nt < 4; ++nt)
                Bv[d][nt] = *(const f16x8*)&WB[((size_t)(nt * 32 + kb + kc)) * 512 + lo8];
        }
    };

    LDA(0, 0); LDA(1, 1); LDA(2, 2); LDA(3, 3);
    LDB(0, 0); LDB(1, 1);

    #pragma unroll
    for (int kc = 0; kc < 16; ++kc) {
        const int sa = kc & 3, sb = kc & 1;
        f16x8 af;
        af[0] = (_Float16)A0[sa].x; af[1] = (_Float16)A0[sa].y;
        af[2] = (_Float16)A0[sa].z; af[3] = (_Float16)A0[sa].w;
        af[4] = (_Float16)A1[sa].x; af[5] = (_Float16)A1[sa].y;
        af[6] = (_Float16)A1[sa].z; af[7] = (_Float16)A1[sa].w;
        #pragma unroll
        for (int nt = 0; nt < 4; ++nt)
            acc0[nt] = mfma32(af, Bq[sb][nt], acc0[nt]);
        if (mode) {
            #pragma unroll
            for (int nt = 0; nt < 4; ++nt)
                acc1[nt] = mfma32(af, Bv[sb][nt], acc1[nt]);
        }
        if (kc < 12) LDA(sa, kc + 4);
        if (kc < 14) LDB(sb, kc + 2);
    }

    const float* __restrict__ bias0 = mode ? bk : bq;
    const int bb = r0 >> 11, s0 = r0 & (SEQ - 1);

    // ---- combine K-halves for Q/K result ----
    if (khalf == 1) {
        #pragma unroll
        for (int nt = 0; nt < 4; ++nt)
            #pragma unroll
            for (int r = 0; r < 4; ++r)
                TL[rowgrp * 16 + quad * 4 + r][nt * 16 + l15] = acc0[nt][r];
    }
    __syncthreads();
    if (khalf == 0) {
        #pragma unroll
        for (int nt = 0; nt < 4; ++nt) {
            float bs = bias0[nt * 16 + l15];
            #pragma unroll
            for (int r = 0; r < 4; ++r) {
                int rr = rowgrp * 16 + quad * 4 + r;
                TL[rr][nt * 16 + l15] = acc0[nt][r] + TL[rr][nt * 16 + l15] + bs;
            }
        }
    }
    __syncthreads();

    if (mode == 0) {
        int row = tid >> 3, c8 = (tid & 7) * 8;
        f16x8 o;
        #pragma unroll
        for (int j = 0; j < 8; ++j) o[j] = (_Float16)TL[row][c8 + j];
        *(f16x8*)&Qb[(size_t)(r0 + row) * 64 + c8] = o;
    } else {
        // ---- pack Kf fragments ----
        {
            int c = tid >> 7, hf = (tid >> 6) & 1, ln = tid & 63;
            f16x8 w;
            #pragma unroll
            for (int j = 0; j < 8; ++j)
                w[j] = (_Float16)TL[c * 16 + (ln & 15)][hf * 32 + ((ln >> 4) << 3) + j];
            *(f16x8*)&Kf[(((size_t)(bb * 128 + (s0 >> 4) + c)) * 2 + hf) * 512 + ln * 8] = w;
        }
        __syncthreads();
        // ---- combine K-halves for V ----
        if (khalf == 1) {
            #pragma unroll
            for (int nt = 0; nt < 4; ++nt)
                #pragma unroll
                for (int r = 0; r < 4; ++r)
                    TL[rowgrp * 16 + quad * 4 + r][nt * 16 + l15] = acc1[nt][r];
        }
        __syncthreads();
        if (khalf == 0) {
            #pragma unroll
            for (int nt = 0; nt < 4; ++nt) {
                float bs = bv[nt * 16 + l15];
                #pragma unroll
                for (int r = 0; r < 4; ++r) {
                    int rr = rowgrp * 16 + quad * 4 + r;
                    TL[rr][nt * 16 + l15] = acc1[nt][r] + TL[rr][nt * 16 + l15] + bs;
                }
            }
        }
        __syncthreads();
        // ---- pack Vf fragments + Vts sums ----
        {
            int c2 = tid >> 8, ht = (tid >> 6) & 3, ln = tid & 63;
            f16x8 w;
            #pragma unroll
            for (int j = 0; j < 8; ++j)
                w[j] = (_Float16)TL[c2 * 32 + ((j >> 2) << 4) + ((ln >> 4) << 2) + (j & 3)][ht * 16 + (ln & 15)];
            *(f16x8*)&Vf[(((size_t)(bb * 64 + (s0 >> 5) + c2)) * 4 + ht) * 512 + ln * 8] = w;
        }
        if (tid < 256) {
            int h = tid & 63, wv = tid >> 6;
            float s = 0.f;
            #pragma unroll
            for (int i = 0; i < 16; ++i) s += TL[wv * 16 + i][h];
            Vts[((size_t)bb * 128 + (s0 >> 4) + wv) * 64 + h] = s;
        }
    }
}

// ---------------------------------------------------------------------------
// Kernel 2: suffix sums of 16-row V tile sums.
// ---------------------------------------------------------------------------
__global__ __launch_bounds__(256) void vsuf_kernel(
    const float* __restrict__ Vts, float* __restrict__ Vsuf)
{
    const int b = blockIdx.x, hh = blockIdx.y;
    const int tid = threadIdx.x;
    const int seg = tid >> 5, hl = tid & 31, h = (hh << 5) + hl;
    __shared__ float segsum[8][33];
    float vals[16];
    const float* src = Vts + ((size_t)b * 128 + seg * 16) * 64 + h;
    float s = 0.f;
    #pragma unroll
    for (int i = 0; i < 16; ++i) { vals[i] = src[i * 64]; s += vals[i]; }
    segsum[seg][hl] = s;
    __syncthreads();
    float run = 0.f;
    #pragma unroll
    for (int ss = 7; ss >= 0; --ss) if (ss > seg) run += segsum[ss][hl];
    float* dst = Vsuf + ((size_t)b * 128 + seg * 16) * 64 + h;
    #pragma unroll
    for (int i = 15; i >= 0; --i) { run += vals[i]; dst[i * 64] = run; }
}

// ---------------------------------------------------------------------------
// Kernel 3: attention. One 32-row q-tile per block (grid 64 x B); each wave
// handles both 16-row subtiles for its kc2 subset (stride 4) -> 28 MFMA per
// 4 KB of K+V. Ping-pong register buffers, no copies, no k-loop barriers.
// ---------------------------------------------------------------------------
__global__ __launch_bounds__(256) void attn_kernel(
    const _Float16* __restrict__ Qb, const _Float16* __restrict__ Kf,
    const _Float16* __restrict__ Vf, const float* __restrict__ Vsuf,
    float* __restrict__ out)
{
    const int b = blockIdx.y;
    const int tq = blockIdx.x;   // 0..63, 32-row q-tile
    const int tid = threadIdx.x;
    const int wave = tid >> 6, lane = tid & 63;
    const int l15 = lane & 15, quad = lane >> 4;

    __shared__ float part[4][32][68];
    __shared__ float lpart[4][32];

    const f16x4 ONES4 = {(_Float16)1.f, (_Float16)1.f, (_Float16)1.f, (_Float16)1.f};
    f32x4 zero = {0.f, 0.f, 0.f, 0.f};

    const int qbase = tq << 5;
    const int qgA = qbase + l15, qgB = qgA + 16;

    const _Float16* qpA = Qb + ((size_t)(b * SEQ + qbase + l15) << 6);
    const _Float16* qpB = qpA + (16 << 6);
    f16x8 qfA0 = *(const f16x8*)(qpA + quad * 8);
    f16x8 qfA1 = *(const f16x8*)(qpA + 32 + quad * 8);
    f16x8 qfB0 = *(const f16x8*)(qpB + quad * 8);
    f16x8 qfB1 = *(const f16x8*)(qpB + 32 + quad * 8);

    f32x4 accOA[4], accOB[4], accLA = zero, accLB = zero;
    #pragma unroll
    for (int i = 0; i < 4; ++i) { accOA[i] = zero; accOB[i] = zero; }

    const _Float16* __restrict__ kfb = Kf + (size_t)b * 131072 + lane * 8;
    const _Float16* __restrict__ vfb = Vf + (size_t)b * 131072 + lane * 8;

    f16x8 k0[4], v0[4], k1[4], v1[4];

    auto LDK = [&](f16x8* kd, f16x8* vd, int kc2) {
        const _Float16* kp = kfb + (size_t)kc2 * 2048;
        kd[0] = *(const f16x8*)(kp);
        kd[1] = *(const f16x8*)(kp + 512);
        kd[2] = *(const f16x8*)(kp + 1024);
        kd[3] = *(const f16x8*)(kp + 1536);
        const _Float16* vp = vfb + (size_t)kc2 * 2048;
        vd[0] = *(const f16x8*)(vp);
        vd[1] = *(const f16x8*)(vp + 512);
        vd[2] = *(const f16x8*)(vp + 1024);
        vd[3] = *(const f16x8*)(vp + 1536);
    };

    auto CMP = [&](const f16x8* kd, const f16x8* vd, int kc2) {
        #pragma unroll
        for (int c = 0; c < 2; ++c) {
            f32x4 sA = zero, sB = zero;
            sA = mfma32(kd[2 * c], qfA0, sA);
            sA = mfma32(kd[2 * c + 1], qfA1, sA);
            sB = mfma32(kd[2 * c], qfB0, sB);
            sB = mfma32(kd[2 * c + 1], qfB1, sB);
            const int kqb = (kc2 << 5) + (c << 4) + (quad << 2);
            f16x4 pfA, pfB;
            #pragma unroll
            for (int r = 0; r < 4; ++r) {
                pfA[r] = (_Float16)((kqb + r <= qgA) ? __expf(sA[r] * 0.125f) : 1.0f);
                pfB[r] = (_Float16)((kqb + r <= qgB) ? __expf(sB[r] * 0.125f) : 1.0f);
            }
            #pragma unroll
            for (int ht = 0; ht < 4; ++ht) {
                f16x8 vv = vd[ht];
                f16x4 vh;
                if (c == 0) { vh[0] = vv[0]; vh[1] = vv[1]; vh[2] = vv[2]; vh[3] = vv[3]; }
                else        { vh[0] = vv[4]; vh[1] = vv[5]; vh[2] = vv[6]; vh[3] = vv[7]; }
                accOA[ht] = mfma16(vh, pfA, accOA[ht]);
                accOB[ht] = mfma16(vh, pfB, accOB[ht]);
            }
            accLA = mfma16(ONES4, pfA, accLA);
            accLB = mfma16(ONES4, pfB, accLB);
        }
    };

    const int n2 = tq + 1;
    int i = wave;
    LDK(k0, v0, (i < n2) ? i : 0);
    for (; i < n2; i += 8) {
        const int i1 = i + 4;
        LDK(k1, v1, (i1 < n2) ? i1 : i);
        CMP(k0, v0, i);
        const int i2 = i + 8;
        LDK(k0, v0, (i2 < n2) ? i2 : i);
        if (i1 < n2) CMP(k1, v1, i1);
    }

    #pragma unroll
    for (int ht = 0; ht < 4; ++ht)
        #pragma unroll
        for (int r = 0; r < 4; ++r) {
            part[wave][l15][ht * 16 + quad * 4 + r] = accOA[ht][r];
            part[wave][16 + l15][ht * 16 + quad * 4 + r] = accOB[ht][r];
        }
    if (quad == 0) {
        lpart[wave][l15] = accLA[0];
        lpart[wave][16 + l15] = accLB[0];
    }
    __syncthreads();

    {
        const int q = tid >> 3, hb = (tid & 7) << 3;
        f32x4 o0 = zero, o1 = zero;
        float l = 0.f;
        #pragma unroll
        for (int w = 0; w < 4; ++w) {
            l += lpart[w][q];
            o0 = o0 + *(const f32x4*)&part[w][q][hb];
            o1 = o1 + *(const f32x4*)&part[w][q][hb + 4];
        }
        const int tend = 2 * tq + 2;
        const float nOnes = (float)(SEQ - (tend << 4));
        f32x4 cs0 = zero, cs1 = zero;
        if (tend < 128) {
            const float* cp = &Vsuf[((size_t)(b * 128 + tend) << 6) + hb];
            cs0 = *(const f32x4*)(cp);
            cs1 = *(const f32x4*)(cp + 4);
        }
        const float inv = 1.0f / (l + nOnes);
        f32x4 r0 = (o0 + cs0) * inv;
        f32x4 r1 = (o1 + cs1) * inv;
        float* op = &out[((size_t)(b * SEQ + qbase + q) << 6) + hb];
        *(f32x4*)(op) = r0;
        *(f32x4*)(op + 4) = r1;
    }
}

extern "C" void kernel_launch(void* const* d_in, const int* in_sizes, int n_in,
                              void* d_out, int out_size, void* d_ws, size_t ws_size,
                              hipStream_t stream) {
    const float* x  = (const float*)d_in[0];
    const float* y  = (const float*)d_in[1];
    const float* Wq = (const float*)d_in[2];
    const float* bq = (const float*)d_in[3];
    const float* Wk = (const float*)d_in[4];
    const float* bk = (const float*)d_in[5];
    const float* Wv = (const float*)d_in[6];
    const float* bv = (const float*)d_in[7];
    float* out = (float*)d_out;

    char* ws = (char*)d_ws;
    _Float16* Qb  = (_Float16*)(ws);                           // 2 MB
    _Float16* Kf  = (_Float16*)(ws + (1u << 21));              // 2 MB
    _Float16* Vf  = (_Float16*)(ws + (2u << 21));              // 2 MB
    _Float16* Wf  = (_Float16*)(ws + (3u << 21));              // 384 KB
    float*    Vts = (float*)(ws + (3u << 21) + (512u << 10));  // 256 KB
    float*    Vsf = (float*)(ws + (3u << 21) + (768u << 10));  // 256 KB

    wcvt_kernel<<<dim3(12), 256, 0, stream>>>(Wq, Wk, Wv, Wf);
    proj_kernel<<<dim3(256, 2), 512, 0, stream>>>(x, y, Wf, bq, bk, bv, Qb, Kf, Vf, Vts);
    vsuf_kernel<<<dim3(8, 2), 256, 0, stream>>>(Vts, Vsf);
    attn_kernel<<<dim3(64, 8), 256, 0, stream>>>(Qb, Kf, Vf, Vsf, out);
}